// Round 2
// baseline (159.748 us; speedup 1.0000x reference)
//
#include <hip/hip_runtime.h>

// ---------------- workspace float offsets ----------------
#define WS_WQC   0
#define WS_WKCT  16384   // Wkc stored TRANSPOSED: WkcT[d*128 + row]
#define WS_WVC   32768
#define WS_MOW   49152
#define WS_G     65536
#define WS_GS    69632
#define WS_GD    71680
#define WS_G0    73728
#define WS_GS0   73792
#define WS_GD0   73824
#define WS_FSP   73856
#define WS_FDV   77952
#define WS_FHID  82048
#define WS_FB    90240
#define WS_HID   90368   // 128 * 64 * 64 floats (only if ws is big enough)
#define WS_NEED_HID_BYTES ((size_t)(90368 + 128*64*64) * 4)

// P1: Wqc = wq@w_iq, WkcT = (wk@w_ik)^T, Wvc = wv@w_iv, Mow = mha_out_w@out_w
// plus (if grid==512) hid[b] = relu(hs[b] @ w_hid + b_hid) into WS_HID.
__global__ __launch_bounds__(256) void precompute1(
    const float* __restrict__ wq, const float* __restrict__ wk,
    const float* __restrict__ wv, const float* __restrict__ in_proj_w,
    const float* __restrict__ mha_out_w, const float* __restrict__ out_w,
    const float* __restrict__ hs, const float* __restrict__ w_hid,
    const float* __restrict__ b_hid, float* __restrict__ ws)
{
    __shared__ __align__(16) float sbuf[4224];
    const int tid = threadIdx.x;

    if (blockIdx.x < 256) {
        // ---- weight-product path: 4 mats x 128 rows, 2 rows/block ----
        const int mat  = blockIdx.x >> 6;
        const int rp   = blockIdx.x & 63;
        const int rsel = tid >> 7;
        const int col  = tid & 127;
        const int r    = 2 * rp + rsel;
        const float* A; const float* Bm; int ldb;
        if (mat == 0)      { A = wq;        Bm = in_proj_w;       ldb = 384; }
        else if (mat == 1) { A = wk;        Bm = in_proj_w + 128; ldb = 384; }
        else if (mat == 2) { A = wv;        Bm = in_proj_w + 256; ldb = 384; }
        else               { A = mha_out_w; Bm = out_w;           ldb = 128; }
        sbuf[tid] = A[r * 128 + col];
        __syncthreads();
        float acc = 0.f;
        #pragma unroll 8
        for (int d = 0; d < 128; ++d) acc = fmaf(sbuf[rsel * 128 + d], Bm[d * ldb + col], acc);
        if (mat == 0)      ws[WS_WQC  + r * 128 + col] = acc;
        else if (mat == 1) ws[WS_WKCT + col * 128 + r] = acc;   // transposed
        else if (mat == 2) ws[WS_WVC  + r * 128 + col] = acc;
        else               ws[WS_MOW  + r * 128 + col] = acc;
    } else {
        // ---- hid path: one half-batch (32 rows x 64 cols, K=128) ----
        const int b2 = blockIdx.x - 256;
        const int b = b2 >> 1, half = b2 & 1;
        const float4* src = (const float4*)(hs + b * 8192 + half * 4096);
        for (int k = tid; k < 1024; k += 256) {
            const int row = k >> 5, c = k & 31;
            *(float4*)&sbuf[row * 132 + 4 * c] = src[k];
        }
        __syncthreads();
        const int ty = tid >> 4, tx = tid & 15;   // rows 2ty(+1), cols 4tx..
        float a0c[4] = {0,0,0,0}, a1c[4] = {0,0,0,0};
        for (int d0 = 0; d0 < 128; d0 += 4) {
            const float4 a0 = *(const float4*)&sbuf[(2*ty+0)*132 + d0];
            const float4 a1 = *(const float4*)&sbuf[(2*ty+1)*132 + d0];
            const float* a0p = (const float*)&a0;
            const float* a1p = (const float*)&a1;
            #pragma unroll
            for (int dd = 0; dd < 4; ++dd) {
                const float4 w4 = *(const float4*)&w_hid[(d0+dd)*64 + 4*tx];
                a0c[0] = fmaf(a0p[dd], w4.x, a0c[0]); a0c[1] = fmaf(a0p[dd], w4.y, a0c[1]);
                a0c[2] = fmaf(a0p[dd], w4.z, a0c[2]); a0c[3] = fmaf(a0p[dd], w4.w, a0c[3]);
                a1c[0] = fmaf(a1p[dd], w4.x, a1c[0]); a1c[1] = fmaf(a1p[dd], w4.y, a1c[1]);
                a1c[2] = fmaf(a1p[dd], w4.z, a1c[2]); a1c[3] = fmaf(a1p[dd], w4.w, a1c[3]);
            }
        }
        const float4 bh = *(const float4*)&b_hid[4*tx];
        float* dst = ws + WS_HID + b * 4096 + (32*half + 2*ty) * 64 + 4*tx;
        *(float4*)dst        = make_float4(fmaxf(a0c[0]+bh.x,0.f), fmaxf(a0c[1]+bh.y,0.f),
                                           fmaxf(a0c[2]+bh.z,0.f), fmaxf(a0c[3]+bh.w,0.f));
        *(float4*)(dst + 64) = make_float4(fmaxf(a1c[0]+bh.x,0.f), fmaxf(a1c[1]+bh.y,0.f),
                                           fmaxf(a1c[2]+bh.z,0.f), fmaxf(a1c[3]+bh.w,0.f));
    }
}

// P2: derived tensors (all global reads now coalesced via WkcT)
__global__ __launch_bounds__(128) void precompute2(
    const float* __restrict__ b_sp, const float* __restrict__ b_vel,
    const float* __restrict__ in_proj_b, const float* __restrict__ mha_out_b,
    const float* __restrict__ out_w, const float* __restrict__ out_b,
    float* __restrict__ ws)
{
    const float* Wqc  = ws + WS_WQC;
    const float* WkcT = ws + WS_WKCT;
    const float* Wvc  = ws + WS_WVC;
    const float* Mow  = ws + WS_MOW;
    const int bid = blockIdx.x, tid = threadIdx.x;
    __shared__ float sa[256];

    if (bid < 64) {
        const int r = bid;
        sa[tid] = Wqc[(32 + r) * 128 + tid];
        __syncthreads();
        const int colIdx = (tid < 64) ? 32 + tid : ((tid < 96) ? tid - 64 : tid);
        float* dst = (tid < 64) ? ws + WS_G  + r * 64 + tid
                   : (tid < 96) ? ws + WS_GS + r * 32 + (tid - 64)
                                : ws + WS_GD + r * 32 + (tid - 96);
        float acc = 0.f;
        #pragma unroll 8
        for (int d = 0; d < 128; ++d) acc = fmaf(sa[d], WkcT[d * 128 + colIdx], acc);
        *dst = acc;
    } else if (bid < 96) {
        const int s = bid - 64;
        sa[tid]       = Wvc[s * 128 + tid];
        sa[128 + tid] = Wvc[(96 + s) * 128 + tid];
        __syncthreads();
        float a1 = 0.f, a2 = 0.f;
        #pragma unroll 8
        for (int m = 0; m < 128; ++m) {
            const float mo = Mow[m * 128 + tid];
            a1 = fmaf(sa[m], mo, a1);
            a2 = fmaf(sa[128 + m], mo, a2);
        }
        ws[WS_FSP + s * 128 + tid] = a1;
        ws[WS_FDV + s * 128 + tid] = a2;
    } else if (bid < 160) {
        const int c = bid - 96;
        sa[tid] = Wvc[(32 + c) * 128 + tid];
        __syncthreads();
        float acc = 0.f;
        #pragma unroll 8
        for (int m = 0; m < 128; ++m) acc = fmaf(sa[m], Mow[m * 128 + tid], acc);
        ws[WS_FHID + c * 128 + tid] = acc;
    } else if (bid == 160) {
        float acc = out_b[tid];
        #pragma unroll 8
        for (int m = 0; m < 128; ++m) {
            acc = fmaf(in_proj_b[256 + m], Mow[m * 128 + tid], acc);
            acc = fmaf(mha_out_b[m], out_w[m * 128 + tid], acc);
        }
        ws[WS_FB + tid] = acc;
    } else {
        float qc = in_proj_b[tid];  // b_iq
        #pragma unroll 4
        for (int s = 0; s < 32; ++s) {
            qc = fmaf(fmaxf(b_sp[s], 0.f),  Wqc[s * 128 + tid], qc);
            qc = fmaf(fmaxf(b_vel[s], 0.f), Wqc[(96 + s) * 128 + tid], qc);
        }
        sa[tid] = qc;
        __syncthreads();
        const int colIdx = (tid < 64) ? 32 + tid : ((tid < 96) ? tid - 64 : tid);
        float* dst = (tid < 64) ? ws + WS_G0  + tid
                   : (tid < 96) ? ws + WS_GS0 + (tid - 64)
                                : ws + WS_GD0 + (tid - 96);
        float acc = 0.f;
        #pragma unroll 8
        for (int d = 0; d < 128; ++d) acc = fmaf(sa[d], WkcT[d * 128 + colIdx], acc);
        *dst = acc;
    }
}

// ---------------- LDS layout for main (floats) ----------------
// union region U (5568): s_t(1088) s_sc(1088) s_qs(576) s_qd(576) s_ssp(576) s_sdv(576) s_ah(1088)
//                        [s_hs(4224) aliases U during phase 2 of the fallback path]
// 5568:  s_hid  (64 x 68)
// 9920:  s_hidT (64 x 68)
// 14272: s_obs (256)   14528: s_w (192)   total 14720 floats = 58.9 KB -> 2 blocks/CU
#define L_T    0
#define L_SC   1088
#define L_QS   2176
#define L_QD   2752
#define L_SSP  3328
#define L_SDV  3904
#define L_AH   4480
#define L_HID  5568
#define L_HIDT 9920
#define L_OBS  14272
#define L_W    14528

// Main kernel: 4 blocks per batch, 16 query rows each, 256 threads.
template <bool HIDWS>
__global__ __launch_bounds__(256) void attn_main(
    const float* __restrict__ hs, const float* __restrict__ obs1,
    const float* __restrict__ obs2,
    const float* __restrict__ w_sp, const float* __restrict__ b_sp,
    const float* __restrict__ w_vel, const float* __restrict__ b_vel,
    const float* __restrict__ w_hid, const float* __restrict__ b_hid,
    const float* __restrict__ ws, float* __restrict__ out)
{
    const int tid  = threadIdx.x;
    const int lane = tid & 63;
    const int b    = blockIdx.x >> 2;
    const int i0   = (blockIdx.x & 3) * 16;

    const float* Gm   = ws + WS_G;
    const float* Gs   = ws + WS_GS;
    const float* Gd   = ws + WS_GD;
    const float* g0v  = ws + WS_G0;
    const float* gs0v = ws + WS_GS0;
    const float* gd0v = ws + WS_GD0;
    const float* Fsp  = ws + WS_FSP;
    const float* Fdv  = ws + WS_FDV;
    const float* Fhid = ws + WS_FHID;
    const float* fbv  = ws + WS_FB;

    __shared__ __align__(16) float smem[14720];
    float* const s_t    = smem + L_T;
    float* const s_sc   = smem + L_SC;
    float* const s_qs   = smem + L_QS;
    float* const s_qd   = smem + L_QD;
    float* const s_ssp  = smem + L_SSP;
    float* const s_sdv  = smem + L_SDV;
    float* const s_ah   = smem + L_AH;
    float* const s_hid  = smem + L_HID;
    float* const s_hidT = smem + L_HIDT;
    float* const s_obs  = smem + L_OBS;
    float* const s_w    = smem + L_W;
    float* const s_hs   = smem;  // aliases U, fallback phase 2 only

    // ---- phase 0: small weights + obs staging ----
    if (tid < 192) {
        float v;
        if (tid < 64)       v = w_sp[tid];
        else if (tid < 128) v = w_vel[tid - 64];
        else if (tid < 160) v = b_sp[tid - 128];
        else                v = b_vel[tid - 160];
        s_w[tid] = v;
    }
    if (tid < 64) {
        const int g = b * 64 + tid;
        const float ox = obs2[g * 2 + 0];
        const float oy = obs2[g * 2 + 1];
        const float vx = ox - obs1[g * 2 + 0];
        const float vy = oy - obs1[g * 2 + 1];
        *(float4*)&s_obs[tid * 4] = make_float4(ox, oy, vx, vy);
    }

    // ---- phase 2: hid (+hidT) into LDS ----
    if (HIDWS) {
        const float4* src = (const float4*)(ws + WS_HID + b * 4096);
        for (int k = tid; k < 1024; k += 256) {
            const int row = k >> 4, c4 = (k & 15) * 4;
            const float4 v = src[k];
            *(float4*)&s_hid[row * 68 + c4] = v;
            s_hidT[(c4 + 0) * 68 + row] = v.x;
            s_hidT[(c4 + 1) * 68 + row] = v.y;
            s_hidT[(c4 + 2) * 68 + row] = v.z;
            s_hidT[(c4 + 3) * 68 + row] = v.w;
        }
        __syncthreads();
    } else {
        for (int h = 0; h < 2; ++h) {
            const float4* srcH = (const float4*)(hs + b * 8192 + h * 4096);
            for (int k = tid; k < 1024; k += 256) {
                const int row = k >> 5, c = k & 31;
                *(float4*)&s_hs[row * 132 + 4 * c] = srcH[k];
            }
            __syncthreads();
            const int ty = tid >> 4, tx = tid & 15;
            float a0c[4] = {0,0,0,0}, a1c[4] = {0,0,0,0};
            for (int d0 = 0; d0 < 128; d0 += 4) {
                const float4 a0 = *(const float4*)&s_hs[(2*ty+0)*132 + d0];
                const float4 a1 = *(const float4*)&s_hs[(2*ty+1)*132 + d0];
                const float* a0p = (const float*)&a0;
                const float* a1p = (const float*)&a1;
                #pragma unroll
                for (int dd = 0; dd < 4; ++dd) {
                    const float4 w4 = *(const float4*)&w_hid[(d0+dd)*64 + 4*tx];
                    a0c[0] = fmaf(a0p[dd], w4.x, a0c[0]); a0c[1] = fmaf(a0p[dd], w4.y, a0c[1]);
                    a0c[2] = fmaf(a0p[dd], w4.z, a0c[2]); a0c[3] = fmaf(a0p[dd], w4.w, a0c[3]);
                    a1c[0] = fmaf(a1p[dd], w4.x, a1c[0]); a1c[1] = fmaf(a1p[dd], w4.y, a1c[1]);
                    a1c[2] = fmaf(a1p[dd], w4.z, a1c[2]); a1c[3] = fmaf(a1p[dd], w4.w, a1c[3]);
                }
            }
            const float4 bh = *(const float4*)&b_hid[4*tx];
            float v0[4], v1[4];
            v0[0]=fmaxf(a0c[0]+bh.x,0.f); v0[1]=fmaxf(a0c[1]+bh.y,0.f);
            v0[2]=fmaxf(a0c[2]+bh.z,0.f); v0[3]=fmaxf(a0c[3]+bh.w,0.f);
            v1[0]=fmaxf(a1c[0]+bh.x,0.f); v1[1]=fmaxf(a1c[1]+bh.y,0.f);
            v1[2]=fmaxf(a1c[2]+bh.z,0.f); v1[3]=fmaxf(a1c[3]+bh.w,0.f);
            const int r0 = 32*h + 2*ty;
            *(float4*)&s_hid[(r0+0)*68 + 4*tx] = make_float4(v0[0],v0[1],v0[2],v0[3]);
            *(float4*)&s_hid[(r0+1)*68 + 4*tx] = make_float4(v1[0],v1[1],v1[2],v1[3]);
            #pragma unroll
            for (int cc = 0; cc < 4; ++cc)
                *(float2*)&s_hidT[(4*tx+cc)*68 + r0] = make_float2(v0[cc], v1[cc]);
            __syncthreads();
        }
    }

    // ---- phase 3 (fused): t = hid[i0+ty]@G + g0 ; q = hid[i0+ty]@(Gs|Gd) + bias ----
    {
        const int ty = tid >> 4, tx = tid & 15;
        const int r = i0 + ty;
        const float* Bq  = (tx < 8) ? Gs : Gd;
        const float* bq0 = (tx < 8) ? gs0v : gd0v;
        float* dstq      = (tx < 8) ? s_qs : s_qd;
        const int nc = (tx & 7) * 4;
        const float4 gb = *(const float4*)&g0v[4*tx];
        const float4 qb = *(const float4*)&bq0[nc];
        float aT[4] = {gb.x, gb.y, gb.z, gb.w};
        float aQ[4] = {qb.x, qb.y, qb.z, qb.w};
        for (int k0 = 0; k0 < 64; k0 += 4) {
            const float4 a = *(const float4*)&s_hid[r * 68 + k0];
            const float* ap = (const float*)&a;
            #pragma unroll
            for (int kk = 0; kk < 4; ++kk) {
                const float4 g4 = *(const float4*)&Gm[(k0+kk)*64 + 4*tx];
                const float4 q4 = *(const float4*)&Bq[(k0+kk)*32 + nc];
                aT[0] = fmaf(ap[kk], g4.x, aT[0]); aT[1] = fmaf(ap[kk], g4.y, aT[1]);
                aT[2] = fmaf(ap[kk], g4.z, aT[2]); aT[3] = fmaf(ap[kk], g4.w, aT[3]);
                aQ[0] = fmaf(ap[kk], q4.x, aQ[0]); aQ[1] = fmaf(ap[kk], q4.y, aQ[1]);
                aQ[2] = fmaf(ap[kk], q4.z, aQ[2]); aQ[3] = fmaf(ap[kk], q4.w, aQ[3]);
            }
        }
        *(float4*)&s_t[ty * 68 + 4*tx] = make_float4(aT[0], aT[1], aT[2], aT[3]);
        *(float4*)&dstq[ty * 36 + nc]  = make_float4(aQ[0], aQ[1], aQ[2], aQ[3]);
    }
    __syncthreads();

    // ---- phase 4: qh = t @ hid^T -> s_sc ----
    {
        const int ty = tid >> 4, tx = tid & 15;
        float q[4] = {0,0,0,0};
        for (int c0 = 0; c0 < 64; c0 += 4) {
            const float4 t4 = *(const float4*)&s_t[ty * 68 + c0];
            const float* tp = (const float*)&t4;
            #pragma unroll
            for (int cc = 0; cc < 4; ++cc) {
                const float4 h4 = *(const float4*)&s_hidT[(c0+cc)*68 + 4*tx];
                q[0] = fmaf(tp[cc], h4.x, q[0]); q[1] = fmaf(tp[cc], h4.y, q[1]);
                q[2] = fmaf(tp[cc], h4.z, q[2]); q[3] = fmaf(tp[cc], h4.w, q[3]);
            }
        }
        *(float4*)&s_sc[ty * 68 + 4*tx] = make_float4(q[0], q[1], q[2], q[3]);
    }
    __syncthreads();

    // ---- phase 5: scores + in-wave softmax (4 rows per wave) ----
    {
        const int wid = tid >> 6;  // 0..3
        float relx[4], rely[4], dvx[4], dvy[4], accr[4];
        const float4 oj = *(const float4*)&s_obs[lane * 4];
        #pragma unroll
        for (int k = 0; k < 4; ++k) {
            const int i = i0 + wid * 4 + k;
            const float4 oi = *(const float4*)&s_obs[i * 4];
            relx[k] = oj.x - oi.x;
            rely[k] = oj.y - oi.y;
            dvx[k]  = (oj.z - oi.z) * 4.f;
            dvy[k]  = (oj.w - oi.w) * 4.f;
            accr[k] = 0.f;
        }
        for (int s0 = 0; s0 < 32; s0 += 4) {
            const float4 w0  = *(const float4*)&s_w[s0];
            const float4 w1  = *(const float4*)&s_w[32 + s0];
            const float4 wv0 = *(const float4*)&s_w[64 + s0];
            const float4 wv1 = *(const float4*)&s_w[96 + s0];
            const float4 bs  = *(const float4*)&s_w[128 + s0];
            const float4 bv  = *(const float4*)&s_w[160 + s0];
            #pragma unroll
            for (int k = 0; k < 4; ++k) {
                const int r = wid * 4 + k;
                const float4 qs4 = *(const float4*)&s_qs[r * 36 + s0];
                const float4 qd4 = *(const float4*)&s_qd[r * 36 + s0];
                float acc = accr[k];
                acc = fmaf(qs4.x, fmaxf(fmaf(relx[k], w0.x, fmaf(rely[k], w1.x, bs.x)), 0.f), acc);
                acc = fmaf(qs4.y, fmaxf(fmaf(relx[k], w0.y, fmaf(rely[k], w1.y, bs.y)), 0.f), acc);
                acc = fmaf(qs4.z, fmaxf(fmaf(relx[k], w0.z, fmaf(rely[k], w1.z, bs.z)), 0.f), acc);
                acc = fmaf(qs4.w, fmaxf(fmaf(relx[k], w0.w, fmaf(rely[k], w1.w, bs.w)), 0.f), acc);
                acc = fmaf(qd4.x, fmaxf(fmaf(dvx[k], wv0.x, fmaf(dvy[k], wv1.x, bv.x)), 0.f), acc);
                acc = fmaf(qd4.y, fmaxf(fmaf(dvx[k], wv0.y, fmaf(dvy[k], wv1.y, bv.y)), 0.f), acc);
                acc = fmaf(qd4.z, fmaxf(fmaf(dvx[k], wv0.z, fmaf(dvy[k], wv1.z, bv.z)), 0.f), acc);
                acc = fmaf(qd4.w, fmaxf(fmaf(dvx[k], wv0.w, fmaf(dvy[k], wv1.w, bv.w)), 0.f), acc);
                accr[k] = acc;
            }
        }
        const float scale = 0.08838834764831845f;  // 1/sqrt(128)
        #pragma unroll
        for (int k = 0; k < 4; ++k) {
            const int r = wid * 4 + k;
            const float sc = (s_sc[r * 68 + lane] + accr[k]) * scale;
            float m = sc;
            #pragma unroll
            for (int off = 32; off > 0; off >>= 1) m = fmaxf(m, __shfl_xor(m, off, 64));
            const float e = __expf(sc - m);
            float sum = e;
            #pragma unroll
            for (int off = 32; off > 0; off >>= 1) sum += __shfl_xor(sum, off, 64);
            s_sc[r * 68 + lane] = e / sum;
        }
    }
    __syncthreads();

    // ---- phase 6: ssp/sdv (attn-weighted embeds) ; ah = attn @ hid ----
    {
        // 6a: 16 rows x 16 thread-groups; sx<8 -> sp cols, sx>=8 -> dv cols
        const int r6 = tid >> 4, sx = tid & 15;
        const int i = i0 + r6;
        const bool isSp = (sx < 8);
        const int nc = (sx & 7) * 4;
        const float4 wA = *(const float4*)&s_w[(isSp ? 0 : 64) + nc];
        const float4 wB = *(const float4*)&s_w[(isSp ? 32 : 96) + nc];
        const float4 bb = *(const float4*)&s_w[(isSp ? 128 : 160) + nc];
        const float4 oi = *(const float4*)&s_obs[i * 4];
        float c0=0, c1=0, c2=0, c3=0;
        for (int j0 = 0; j0 < 64; j0 += 4) {
            const float4 a4 = *(const float4*)&s_sc[r6 * 68 + j0];
            const float* ap = (const float*)&a4;
            #pragma unroll
            for (int jj = 0; jj < 4; ++jj) {
                const float4 oj4 = *(const float4*)&s_obs[(j0 + jj) * 4];
                const float a = ap[jj];
                const float ux = isSp ? (oj4.x - oi.x) : (oj4.z - oi.z) * 4.f;
                const float uy = isSp ? (oj4.y - oi.y) : (oj4.w - oi.w) * 4.f;
                c0 = fmaf(a, fmaxf(fmaf(ux, wA.x, fmaf(uy, wB.x, bb.x)), 0.f), c0);
                c1 = fmaf(a, fmaxf(fmaf(ux, wA.y, fmaf(uy, wB.y, bb.y)), 0.f), c1);
                c2 = fmaf(a, fmaxf(fmaf(ux, wA.z, fmaf(uy, wB.z, bb.z)), 0.f), c2);
                c3 = fmaf(a, fmaxf(fmaf(ux, wA.w, fmaf(uy, wB.w, bb.w)), 0.f), c3);
            }
        }
        float* dst = isSp ? (s_ssp + r6 * 36 + nc) : (s_sdv + r6 * 36 + nc);
        *(float4*)dst = make_float4(c0, c1, c2, c3);

        // 6b: ah = attn @ hid (16 x 64)
        const int ty = tid >> 4, tx = tid & 15;
        float h[4] = {0,0,0,0};
        for (int j0 = 0; j0 < 64; j0 += 4) {
            const float4 at4 = *(const float4*)&s_sc[ty * 68 + j0];
            const float* atp = (const float*)&at4;
            #pragma unroll
            for (int jj = 0; jj < 4; ++jj) {
                const float4 h4 = *(const float4*)&s_hid[(j0+jj)*68 + 4*tx];
                h[0] = fmaf(atp[jj], h4.x, h[0]); h[1] = fmaf(atp[jj], h4.y, h[1]);
                h[2] = fmaf(atp[jj], h4.z, h[2]); h[3] = fmaf(atp[jj], h4.w, h[3]);
            }
        }
        *(float4*)&s_ah[ty * 68 + 4*tx] = make_float4(h[0], h[1], h[2], h[3]);
    }
    __syncthreads();

    // ---- phase 7: out = ssp@Fsp + sdv@Fdv + ah@Fhid + fb ----
    {
        const int ty = tid >> 4, tx = tid & 15;  // row ty, cols 8tx..8tx+7
        const float4 fba = *(const float4*)&fbv[8*tx];
        const float4 fbb = *(const float4*)&fbv[8*tx + 4];
        float oa[4] = {fba.x, fba.y, fba.z, fba.w};
        float ob[4] = {fbb.x, fbb.y, fbb.z, fbb.w};

        #define ACC_TERM(SMAT, LD, FMAT, KMAX)                                        \
        for (int k0 = 0; k0 < (KMAX); k0 += 4) {                                      \
            const float4 a4 = *(const float4*)&SMAT[ty * (LD) + k0];                  \
            const float* ap = (const float*)&a4;                                      \
            _Pragma("unroll")                                                         \
            for (int kk = 0; kk < 4; ++kk) {                                          \
                const float4 fa = *(const float4*)&FMAT[(k0+kk)*128 + 8*tx];          \
                const float4 fq = *(const float4*)&FMAT[(k0+kk)*128 + 8*tx + 4];      \
                oa[0] = fmaf(ap[kk], fa.x, oa[0]); oa[1] = fmaf(ap[kk], fa.y, oa[1]); \
                oa[2] = fmaf(ap[kk], fa.z, oa[2]); oa[3] = fmaf(ap[kk], fa.w, oa[3]); \
                ob[0] = fmaf(ap[kk], fq.x, ob[0]); ob[1] = fmaf(ap[kk], fq.y, ob[1]); \
                ob[2] = fmaf(ap[kk], fq.z, ob[2]); ob[3] = fmaf(ap[kk], fq.w, ob[3]); \
            }                                                                         \
        }
        ACC_TERM(s_ssp, 36, Fsp, 32)
        ACC_TERM(s_sdv, 36, Fdv, 32)
        ACC_TERM(s_ah,  68, Fhid, 64)
        #undef ACC_TERM

        const int gr = (b * 64 + i0 + ty) * 128;
        *(float4*)&out[gr + 8*tx]     = make_float4(oa[0], oa[1], oa[2], oa[3]);
        *(float4*)&out[gr + 8*tx + 4] = make_float4(ob[0], ob[1], ob[2], ob[3]);
    }
}

extern "C" void kernel_launch(void* const* d_in, const int* in_sizes, int n_in,
                              void* d_out, int out_size, void* d_ws, size_t ws_size,
                              hipStream_t stream) {
    const float* hs        = (const float*)d_in[0];
    const float* obs1      = (const float*)d_in[1];
    const float* obs2      = (const float*)d_in[2];
    const float* w_sp      = (const float*)d_in[3];
    const float* b_sp      = (const float*)d_in[4];
    const float* w_vel     = (const float*)d_in[5];
    const float* b_vel     = (const float*)d_in[6];
    const float* w_hid     = (const float*)d_in[7];
    const float* b_hid     = (const float*)d_in[8];
    const float* wq        = (const float*)d_in[9];
    const float* wk        = (const float*)d_in[10];
    const float* wv        = (const float*)d_in[11];
    const float* in_proj_w = (const float*)d_in[12];
    const float* in_proj_b = (const float*)d_in[13];
    const float* mha_out_w = (const float*)d_in[14];
    const float* mha_out_b = (const float*)d_in[15];
    const float* out_w     = (const float*)d_in[16];
    const float* out_b     = (const float*)d_in[17];
    float* ws  = (float*)d_ws;
    float* out = (float*)d_out;

    const bool hidws = (ws_size >= WS_NEED_HID_BYTES);

    precompute1<<<hidws ? 512 : 256, 256, 0, stream>>>(
        wq, wk, wv, in_proj_w, mha_out_w, out_w, hs, w_hid, b_hid, ws);
    precompute2<<<162, 128, 0, stream>>>(
        b_sp, b_vel, in_proj_b, mha_out_b, out_w, out_b, ws);
    if (hidws) {
        attn_main<true><<<512, 256, 0, stream>>>(hs, obs1, obs2, w_sp, b_sp, w_vel, b_vel,
                                                 w_hid, b_hid, ws, out);
    } else {
        attn_main<false><<<512, 256, 0, stream>>>(hs, obs1, obs2, w_sp, b_sp, w_vel, b_vel,
                                                  w_hid, b_hid, ws, out);
    }
}

// Round 3
// 140.394 us; speedup vs baseline: 1.1379x; 1.1379x over previous
//
#include <hip/hip_runtime.h>

// ---------------- workspace float offsets ----------------
#define WS_WQC   0        // wq@w_iq          128x128 row-major
#define WS_WKC   16384    // wk@w_ik          128x128 row-major
#define WS_WVC   32768    // wv@w_iv          128x128 row-major
#define WS_MOW   49152    // mha_out_w@out_w  128x128 row-major
#define WS_GQ    65536    // [64][128]: cols 0..63 G, 64..95 Gs, 96..127 Gd
#define WS_G0Q   73728    // [128] biases in same col order
#define WS_FALL  73856    // [128][128]: rows 0..31 Fsp, 32..63 Fdv, 64..127 Fhid
#define WS_FB    90240    // [128]
#define WS_HID   90368    // [128 batches][64][64] relu(hs@w_hid+b_hid)
#define WS_NEED_HID_BYTES ((size_t)(90368 + 128*64*64) * 4)

// P1: weight products (+ per-batch hid into ws when workspace allows)
__global__ __launch_bounds__(256) void precompute1(
    const float* __restrict__ wq, const float* __restrict__ wk,
    const float* __restrict__ wv, const float* __restrict__ in_proj_w,
    const float* __restrict__ mha_out_w, const float* __restrict__ out_w,
    const float* __restrict__ hs, const float* __restrict__ w_hid,
    const float* __restrict__ b_hid, float* __restrict__ ws)
{
    __shared__ __align__(16) float sbuf[4224];
    const int tid = threadIdx.x;

    if (blockIdx.x < 256) {
        // 4 mats x 128 rows, 2 rows/block, all writes row-major coalesced
        const int mat  = blockIdx.x >> 6;
        const int rp   = blockIdx.x & 63;
        const int rsel = tid >> 7;
        const int col  = tid & 127;
        const int r    = 2 * rp + rsel;
        const float* A; const float* Bm; int ldb; float* C;
        if (mat == 0)      { A = wq;        Bm = in_proj_w;       ldb = 384; C = ws + WS_WQC; }
        else if (mat == 1) { A = wk;        Bm = in_proj_w + 128; ldb = 384; C = ws + WS_WKC; }
        else if (mat == 2) { A = wv;        Bm = in_proj_w + 256; ldb = 384; C = ws + WS_WVC; }
        else               { A = mha_out_w; Bm = out_w;           ldb = 128; C = ws + WS_MOW; }
        sbuf[tid] = A[r * 128 + col];
        __syncthreads();
        float acc = 0.f;
        #pragma unroll 8
        for (int d = 0; d < 128; ++d) acc = fmaf(sbuf[rsel * 128 + d], Bm[d * ldb + col], acc);
        C[r * 128 + col] = acc;
    } else {
        // hid path: one half-batch (32 rows x 64 cols, K=128)
        const int b2 = blockIdx.x - 256;
        const int b = b2 >> 1, half = b2 & 1;
        const float4* src = (const float4*)(hs + b * 8192 + half * 4096);
        for (int k = tid; k < 1024; k += 256) {
            const int row = k >> 5, c = k & 31;
            *(float4*)&sbuf[row * 132 + 4 * c] = src[k];
        }
        __syncthreads();
        const int ty = tid >> 4, tx = tid & 15;
        float a0c[4] = {0,0,0,0}, a1c[4] = {0,0,0,0};
        for (int d0 = 0; d0 < 128; d0 += 4) {
            const float4 a0 = *(const float4*)&sbuf[(2*ty+0)*132 + d0];
            const float4 a1 = *(const float4*)&sbuf[(2*ty+1)*132 + d0];
            const float* a0p = (const float*)&a0;
            const float* a1p = (const float*)&a1;
            #pragma unroll
            for (int dd = 0; dd < 4; ++dd) {
                const float4 w4 = *(const float4*)&w_hid[(d0+dd)*64 + 4*tx];
                a0c[0] = fmaf(a0p[dd], w4.x, a0c[0]); a0c[1] = fmaf(a0p[dd], w4.y, a0c[1]);
                a0c[2] = fmaf(a0p[dd], w4.z, a0c[2]); a0c[3] = fmaf(a0p[dd], w4.w, a0c[3]);
                a1c[0] = fmaf(a1p[dd], w4.x, a1c[0]); a1c[1] = fmaf(a1p[dd], w4.y, a1c[1]);
                a1c[2] = fmaf(a1p[dd], w4.z, a1c[2]); a1c[3] = fmaf(a1p[dd], w4.w, a1c[3]);
            }
        }
        const float4 bh = *(const float4*)&b_hid[4*tx];
        float* dst = ws + WS_HID + b * 4096 + (32*half + 2*ty) * 64 + 4*tx;
        *(float4*)dst        = make_float4(fmaxf(a0c[0]+bh.x,0.f), fmaxf(a0c[1]+bh.y,0.f),
                                           fmaxf(a0c[2]+bh.z,0.f), fmaxf(a0c[3]+bh.w,0.f));
        *(float4*)(dst + 64) = make_float4(fmaxf(a1c[0]+bh.x,0.f), fmaxf(a1c[1]+bh.y,0.f),
                                           fmaxf(a1c[2]+bh.z,0.f), fmaxf(a1c[3]+bh.w,0.f));
    }
}

// P2: derived fused tensors GQ / g0q / F_all / fb
__global__ __launch_bounds__(128) void precompute2(
    const float* __restrict__ b_sp, const float* __restrict__ b_vel,
    const float* __restrict__ in_proj_b, const float* __restrict__ mha_out_b,
    const float* __restrict__ out_w, const float* __restrict__ out_b,
    float* __restrict__ ws)
{
    const float* Wqc = ws + WS_WQC;
    const float* Wkc = ws + WS_WKC;
    const float* Wvc = ws + WS_WVC;
    const float* Mow = ws + WS_MOW;
    const int bid = blockIdx.x, tid = threadIdx.x;
    __shared__ float sa[128];

    if (bid < 64) {
        // GQ row k: Wqc[32+k] . Wkc[perm(j)]
        const int k = bid;
        sa[tid] = Wqc[(32 + k) * 128 + tid];
        __syncthreads();
        const int j = tid;
        const int pj = (j < 64) ? 32 + j : ((j < 96) ? j - 64 : j);
        const float* brow = Wkc + pj * 128;
        float acc = 0.f;
        #pragma unroll 8
        for (int d = 0; d < 128; ++d) acc = fmaf(sa[d], brow[d], acc);
        ws[WS_GQ + k * 128 + j] = acc;
    } else if (bid < 192) {
        // F_all row k2: Wvc[permF(k2)] @ Mow
        const int k2 = bid - 64;
        const int srcRow = (k2 < 32) ? k2 : ((k2 < 64) ? 96 + (k2 - 32) : 32 + (k2 - 64));
        sa[tid] = Wvc[srcRow * 128 + tid];
        __syncthreads();
        float acc = 0.f;
        #pragma unroll 8
        for (int m = 0; m < 128; ++m) acc = fmaf(sa[m], Mow[m * 128 + tid], acc);
        ws[WS_FALL + k2 * 128 + tid] = acc;
    } else if (bid == 192) {
        float acc = out_b[tid];
        #pragma unroll 8
        for (int m = 0; m < 128; ++m) {
            acc = fmaf(in_proj_b[256 + m], Mow[m * 128 + tid], acc);
            acc = fmaf(mha_out_b[m], out_w[m * 128 + tid], acc);
        }
        ws[WS_FB + tid] = acc;
    } else {
        // qc then g0q
        float qc = in_proj_b[tid];  // b_iq
        #pragma unroll 4
        for (int s = 0; s < 32; ++s) {
            qc = fmaf(fmaxf(b_sp[s], 0.f),  Wqc[s * 128 + tid], qc);
            qc = fmaf(fmaxf(b_vel[s], 0.f), Wqc[(96 + s) * 128 + tid], qc);
        }
        sa[tid] = qc;
        __syncthreads();
        const int j = tid;
        const int pj = (j < 64) ? 32 + j : ((j < 96) ? j - 64 : j);
        const float* brow = Wkc + pj * 128;
        float acc = 0.f;
        #pragma unroll 8
        for (int d = 0; d < 128; ++d) acc = fmaf(sa[d], brow[d], acc);
        ws[WS_G0Q + j] = acc;
    }
}

// ---------------- attn_main v3: wave-owns-2-rows, one barrier ----------------
// LDS: s_hid 64x66 (4224) | s_obs 256 | per-wave scratch 4x384:
//   t-region 128 ([r][64]: t, later ssp|sdv), q-region 128 ([r][qs32|qd32], later ah),
//   a-region 128 ([j][2] attn)
#define L_OBS  4224
#define L_WV   4480
// total 4480 + 4*384 = 6016 floats = 24.1 KB -> grid-limited 4 blocks/CU, 16 waves/CU

template <bool HIDWS>
__global__ __launch_bounds__(256) void attn_main(
    const float* __restrict__ hs, const float* __restrict__ obs1,
    const float* __restrict__ obs2,
    const float* __restrict__ w_sp, const float* __restrict__ b_sp,
    const float* __restrict__ w_vel, const float* __restrict__ b_vel,
    const float* __restrict__ w_hid, const float* __restrict__ b_hid,
    const float* __restrict__ ws, float* __restrict__ out)
{
    const int tid = threadIdx.x;
    const int l   = tid & 63;
    const int w   = tid >> 6;
    const int b   = blockIdx.x >> 3;
    const int i0  = (blockIdx.x & 7) * 8;

    const float* GQ   = ws + WS_GQ;
    const float* g0q  = ws + WS_G0Q;
    const float* Fall = ws + WS_FALL;
    const float* fbv  = ws + WS_FB;

    __shared__ __align__(16) float smem[6016];
    float* const s_hid = smem;            // stride 66
    float* const s_obs = smem + L_OBS;    // [j][4] = {o2x,o2y,vx,vy}
    float* const tt = smem + L_WV + w * 384;        // 128: [r][64]
    float* const qq = smem + L_WV + w * 384 + 128;  // 128: [r][qs|qd]
    float* const aa = smem + L_WV + w * 384 + 256;  // 128: [j][2]

    // ---- staging ----
    if (tid < 64) {
        const int g = b * 64 + tid;
        const float2 o2 = ((const float2*)obs2)[g];
        const float2 o1 = ((const float2*)obs1)[g];
        *(float4*)&s_obs[tid * 4] = make_float4(o2.x, o2.y, o2.x - o1.x, o2.y - o1.y);
    }
    if (HIDWS) {
        const float4* src = (const float4*)(ws + WS_HID + b * 4096);
        #pragma unroll
        for (int k = tid; k < 1024; k += 256) {
            const int row = k >> 4, c4 = (k & 15) * 4;
            const float4 v = src[k];
            *(float2*)&s_hid[row * 66 + c4]     = make_float2(v.x, v.y);
            *(float2*)&s_hid[row * 66 + c4 + 2] = make_float2(v.z, v.w);
        }
    } else {
        // fallback: compute hid from hs directly (slow path, correctness only)
        const int r = tid >> 2, qseg = (tid & 3) * 16;
        float acc[16];
        #pragma unroll
        for (int c = 0; c < 16; ++c) acc[c] = b_hid[qseg + c];
        for (int k = 0; k < 128; ++k) {
            const float a = hs[b * 8192 + r * 128 + k];
            #pragma unroll
            for (int c4 = 0; c4 < 4; ++c4) {
                const float4 w4 = *(const float4*)&w_hid[k * 64 + qseg + 4 * c4];
                acc[4*c4+0] = fmaf(a, w4.x, acc[4*c4+0]);
                acc[4*c4+1] = fmaf(a, w4.y, acc[4*c4+1]);
                acc[4*c4+2] = fmaf(a, w4.z, acc[4*c4+2]);
                acc[4*c4+3] = fmaf(a, w4.w, acc[4*c4+3]);
            }
        }
        #pragma unroll
        for (int c = 0; c < 16; c += 2)
            *(float2*)&s_hid[r * 66 + qseg + c] =
                make_float2(fmaxf(acc[c], 0.f), fmaxf(acc[c+1], 0.f));
    }
    __syncthreads();
    // ---- no more block barriers: each wave owns rows i0+2w, i0+2w+1 ----

    const int rg0 = i0 + 2 * w;       // global-in-batch row of r=0

    // ---- phase 3: t[r][2l..2l+1] / q[r][..] = hid[row] @ GQ + g0q ----
    {
        const float2 bias = *(const float2*)&g0q[2 * l];
        float a00 = bias.x, a01 = bias.y, a10 = bias.x, a11 = bias.y;
        const float* h0p = &s_hid[rg0 * 66];
        const float* h1p = &s_hid[(rg0 + 1) * 66];
        for (int k0 = 0; k0 < 64; k0 += 2) {
            const float2 h0 = *(const float2*)&h0p[k0];
            const float2 h1 = *(const float2*)&h1p[k0];
            const float2 g0v = *(const float2*)&GQ[k0 * 128 + 2 * l];
            const float2 g1v = *(const float2*)&GQ[(k0 + 1) * 128 + 2 * l];
            a00 = fmaf(h0.x, g0v.x, fmaf(h0.y, g1v.x, a00));
            a01 = fmaf(h0.x, g0v.y, fmaf(h0.y, g1v.y, a01));
            a10 = fmaf(h1.x, g0v.x, fmaf(h1.y, g1v.x, a10));
            a11 = fmaf(h1.x, g0v.y, fmaf(h1.y, g1v.y, a11));
        }
        if (l < 32) {
            *(float2*)&tt[2 * l]      = make_float2(a00, a01);
            *(float2*)&tt[64 + 2 * l] = make_float2(a10, a11);
        } else {
            *(float2*)&qq[2 * l - 64]  = make_float2(a00, a01);
            *(float2*)&qq[2 * l]       = make_float2(a10, a11);  // 64 + (2l-64)
        }
    }

    // ---- phase 4: qh[r][l] = t[r] . hid[l] (regs) ----
    float sc0 = 0.f, sc1 = 0.f;
    {
        const float* hlp = &s_hid[l * 66];
        for (int c0 = 0; c0 < 64; c0 += 4) {
            const float4 t0 = *(const float4*)&tt[c0];
            const float4 t1 = *(const float4*)&tt[64 + c0];
            const float2 ha = *(const float2*)&hlp[c0];
            const float2 hb = *(const float2*)&hlp[c0 + 2];
            sc0 = fmaf(t0.x, ha.x, fmaf(t0.y, ha.y, fmaf(t0.z, hb.x, fmaf(t0.w, hb.y, sc0))));
            sc1 = fmaf(t1.x, ha.x, fmaf(t1.y, ha.y, fmaf(t1.z, hb.x, fmaf(t1.w, hb.y, sc1))));
        }
    }

    // ---- phase 5: scores + softmax, attn -> aa[j][2] ----
    {
        const float4 oj  = *(const float4*)&s_obs[4 * l];
        const float4 oiA = *(const float4*)&s_obs[4 * rg0];
        const float4 oiB = *(const float4*)&s_obs[4 * (rg0 + 1)];
        const float rxA = oj.x - oiA.x, ryA = oj.y - oiA.y;
        const float dxA = (oj.z - oiA.z) * 4.f, dyA = (oj.w - oiA.w) * 4.f;
        const float rxB = oj.x - oiB.x, ryB = oj.y - oiB.y;
        const float dxB = (oj.z - oiB.z) * 4.f, dyB = (oj.w - oiB.w) * 4.f;
        float e0 = 0.f, e1 = 0.f;
        for (int s0 = 0; s0 < 32; s0 += 4) {
            const float4 qsA = *(const float4*)&qq[s0];
            const float4 qsB = *(const float4*)&qq[64 + s0];
            const float4 qdA = *(const float4*)&qq[32 + s0];
            const float4 qdB = *(const float4*)&qq[96 + s0];
            const float4 w0  = *(const float4*)&w_sp[s0];
            const float4 w1  = *(const float4*)&w_sp[32 + s0];
            const float4 bs  = *(const float4*)&b_sp[s0];
            const float4 wv0 = *(const float4*)&w_vel[s0];
            const float4 wv1 = *(const float4*)&w_vel[32 + s0];
            const float4 bv  = *(const float4*)&b_vel[s0];
            e0 = fmaf(qsA.x, fmaxf(fmaf(rxA, w0.x, fmaf(ryA, w1.x, bs.x)), 0.f), e0);
            e0 = fmaf(qsA.y, fmaxf(fmaf(rxA, w0.y, fmaf(ryA, w1.y, bs.y)), 0.f), e0);
            e0 = fmaf(qsA.z, fmaxf(fmaf(rxA, w0.z, fmaf(ryA, w1.z, bs.z)), 0.f), e0);
            e0 = fmaf(qsA.w, fmaxf(fmaf(rxA, w0.w, fmaf(ryA, w1.w, bs.w)), 0.f), e0);
            e0 = fmaf(qdA.x, fmaxf(fmaf(dxA, wv0.x, fmaf(dyA, wv1.x, bv.x)), 0.f), e0);
            e0 = fmaf(qdA.y, fmaxf(fmaf(dxA, wv0.y, fmaf(dyA, wv1.y, bv.y)), 0.f), e0);
            e0 = fmaf(qdA.z, fmaxf(fmaf(dxA, wv0.z, fmaf(dyA, wv1.z, bv.z)), 0.f), e0);
            e0 = fmaf(qdA.w, fmaxf(fmaf(dxA, wv0.w, fmaf(dyA, wv1.w, bv.w)), 0.f), e0);
            e1 = fmaf(qsB.x, fmaxf(fmaf(rxB, w0.x, fmaf(ryB, w1.x, bs.x)), 0.f), e1);
            e1 = fmaf(qsB.y, fmaxf(fmaf(rxB, w0.y, fmaf(ryB, w1.y, bs.y)), 0.f), e1);
            e1 = fmaf(qsB.z, fmaxf(fmaf(rxB, w0.z, fmaf(ryB, w1.z, bs.z)), 0.f), e1);
            e1 = fmaf(qsB.w, fmaxf(fmaf(rxB, w0.w, fmaf(ryB, w1.w, bs.w)), 0.f), e1);
            e1 = fmaf(qdB.x, fmaxf(fmaf(dxB, wv0.x, fmaf(dyB, wv1.x, bv.x)), 0.f), e1);
            e1 = fmaf(qdB.y, fmaxf(fmaf(dxB, wv0.y, fmaf(dyB, wv1.y, bv.y)), 0.f), e1);
            e1 = fmaf(qdB.z, fmaxf(fmaf(dxB, wv0.z, fmaf(dyB, wv1.z, bv.z)), 0.f), e1);
            e1 = fmaf(qdB.w, fmaxf(fmaf(dxB, wv0.w, fmaf(dyB, wv1.w, bv.w)), 0.f), e1);
        }
        const float scale = 0.08838834764831845f;  // 1/sqrt(128)
        float v0 = (sc0 + e0) * scale;
        float v1 = (sc1 + e1) * scale;
        float m0 = v0, m1 = v1;
        #pragma unroll
        for (int off = 32; off > 0; off >>= 1) {
            m0 = fmaxf(m0, __shfl_xor(m0, off, 64));
            m1 = fmaxf(m1, __shfl_xor(m1, off, 64));
        }
        const float ex0 = __expf(v0 - m0);
        const float ex1 = __expf(v1 - m1);
        float su0 = ex0, su1 = ex1;
        #pragma unroll
        for (int off = 32; off > 0; off >>= 1) {
            su0 += __shfl_xor(su0, off, 64);
            su1 += __shfl_xor(su1, off, 64);
        }
        *(float2*)&aa[2 * l] = make_float2(ex0 / su0, ex1 / su1);
    }

    // ---- phase 6a: ssp/sdv -> tt ([r][sp32|dv32]) ----
    {
        const int r = l >> 5, s = l & 31;
        const float w0 = w_sp[s],       w1 = w_sp[32 + s],  bsv = b_sp[s];
        const float u0 = w_vel[s],      u1 = w_vel[32 + s], bvv = b_vel[s];
        const float4 oi = *(const float4*)&s_obs[4 * (rg0 + r)];
        float ssp = 0.f, sdv = 0.f;
        for (int j0 = 0; j0 < 64; j0 += 2) {
            const float4 av  = *(const float4*)&aa[2 * j0];
            const float4 oj0 = *(const float4*)&s_obs[4 * j0];
            const float4 oj1 = *(const float4*)&s_obs[4 * j0 + 4];
            const float a0 = r ? av.y : av.x;
            const float a1 = r ? av.w : av.z;
            {
                const float rx = oj0.x - oi.x, ry = oj0.y - oi.y;
                const float dx = (oj0.z - oi.z) * 4.f, dy = (oj0.w - oi.w) * 4.f;
                ssp = fmaf(a0, fmaxf(fmaf(rx, w0, fmaf(ry, w1, bsv)), 0.f), ssp);
                sdv = fmaf(a0, fmaxf(fmaf(dx, u0, fmaf(dy, u1, bvv)), 0.f), sdv);
            }
            {
                const float rx = oj1.x - oi.x, ry = oj1.y - oi.y;
                const float dx = (oj1.z - oi.z) * 4.f, dy = (oj1.w - oi.w) * 4.f;
                ssp = fmaf(a1, fmaxf(fmaf(rx, w0, fmaf(ry, w1, bsv)), 0.f), ssp);
                sdv = fmaf(a1, fmaxf(fmaf(dx, u0, fmaf(dy, u1, bvv)), 0.f), sdv);
            }
        }
        tt[r * 64 + s]      = ssp;
        tt[r * 64 + 32 + s] = sdv;
    }

    // ---- phase 6b: ah[r][l] = a[r] @ hid -> qq ----
    {
        float ah0 = 0.f, ah1 = 0.f;
        for (int j0 = 0; j0 < 64; j0 += 2) {
            const float4 av = *(const float4*)&aa[2 * j0];
            const float h0 = s_hid[j0 * 66 + l];
            const float h1 = s_hid[(j0 + 1) * 66 + l];
            ah0 = fmaf(av.x, h0, fmaf(av.z, h1, ah0));
            ah1 = fmaf(av.y, h0, fmaf(av.w, h1, ah1));
        }
        qq[l]      = ah0;
        qq[64 + l] = ah1;
    }

    // ---- phase 7: out = [ssp|sdv] @ Fall[0:64] + ah @ Fall[64:128] + fb ----
    {
        const float2 fb2 = *(const float2*)&fbv[2 * l];
        float o00 = fb2.x, o01 = fb2.y, o10 = fb2.x, o11 = fb2.y;
        for (int k0 = 0; k0 < 64; k0 += 4) {
            const float4 A0 = *(const float4*)&tt[k0];
            const float4 A1 = *(const float4*)&tt[64 + k0];
            const float2 f0 = *(const float2*)&Fall[k0 * 128 + 2 * l];
            const float2 f1 = *(const float2*)&Fall[(k0 + 1) * 128 + 2 * l];
            const float2 f2 = *(const float2*)&Fall[(k0 + 2) * 128 + 2 * l];
            const float2 f3 = *(const float2*)&Fall[(k0 + 3) * 128 + 2 * l];
            o00 = fmaf(A0.x, f0.x, fmaf(A0.y, f1.x, fmaf(A0.z, f2.x, fmaf(A0.w, f3.x, o00))));
            o01 = fmaf(A0.x, f0.y, fmaf(A0.y, f1.y, fmaf(A0.z, f2.y, fmaf(A0.w, f3.y, o01))));
            o10 = fmaf(A1.x, f0.x, fmaf(A1.y, f1.x, fmaf(A1.z, f2.x, fmaf(A1.w, f3.x, o10))));
            o11 = fmaf(A1.x, f0.y, fmaf(A1.y, f1.y, fmaf(A1.z, f2.y, fmaf(A1.w, f3.y, o11))));
        }
        for (int k0 = 0; k0 < 64; k0 += 4) {
            const float4 A0 = *(const float4*)&qq[k0];
            const float4 A1 = *(const float4*)&qq[64 + k0];
            const float2 f0 = *(const float2*)&Fall[(64 + k0) * 128 + 2 * l];
            const float2 f1 = *(const float2*)&Fall[(65 + k0) * 128 + 2 * l];
            const float2 f2 = *(const float2*)&Fall[(66 + k0) * 128 + 2 * l];
            const float2 f3 = *(const float2*)&Fall[(67 + k0) * 128 + 2 * l];
            o00 = fmaf(A0.x, f0.x, fmaf(A0.y, f1.x, fmaf(A0.z, f2.x, fmaf(A0.w, f3.x, o00))));
            o01 = fmaf(A0.x, f0.y, fmaf(A0.y, f1.y, fmaf(A0.z, f2.y, fmaf(A0.w, f3.y, o01))));
            o10 = fmaf(A1.x, f0.x, fmaf(A1.y, f1.x, fmaf(A1.z, f2.x, fmaf(A1.w, f3.x, o10))));
            o11 = fmaf(A1.x, f0.y, fmaf(A1.y, f1.y, fmaf(A1.z, f2.y, fmaf(A1.w, f3.y, o11))));
        }
        const int gr = (b * 64 + rg0) * 128 + 2 * l;
        *(float2*)&out[gr]       = make_float2(o00, o01);
        *(float2*)&out[gr + 128] = make_float2(o10, o11);
    }
}

extern "C" void kernel_launch(void* const* d_in, const int* in_sizes, int n_in,
                              void* d_out, int out_size, void* d_ws, size_t ws_size,
                              hipStream_t stream) {
    const float* hs        = (const float*)d_in[0];
    const float* obs1      = (const float*)d_in[1];
    const float* obs2      = (const float*)d_in[2];
    const float* w_sp      = (const float*)d_in[3];
    const float* b_sp      = (const float*)d_in[4];
    const float* w_vel     = (const float*)d_in[5];
    const float* b_vel     = (const float*)d_in[6];
    const float* w_hid     = (const float*)d_in[7];
    const float* b_hid     = (const float*)d_in[8];
    const float* wq        = (const float*)d_in[9];
    const float* wk        = (const float*)d_in[10];
    const float* wv        = (const float*)d_in[11];
    const float* in_proj_w = (const float*)d_in[12];
    const float* in_proj_b = (const float*)d_in[13];
    const float* mha_out_w = (const float*)d_in[14];
    const float* mha_out_b = (const float*)d_in[15];
    const float* out_w     = (const float*)d_in[16];
    const float* out_b     = (const float*)d_in[17];
    float* ws  = (float*)d_ws;
    float* out = (float*)d_out;

    const bool hidws = (ws_size >= WS_NEED_HID_BYTES);

    precompute1<<<hidws ? 512 : 256, 256, 0, stream>>>(
        wq, wk, wv, in_proj_w, mha_out_w, out_w, hs, w_hid, b_hid, ws);
    precompute2<<<194, 128, 0, stream>>>(
        b_sp, b_vel, in_proj_b, mha_out_b, out_w, out_b, ws);
    if (hidws) {
        attn_main<true><<<1024, 256, 0, stream>>>(hs, obs1, obs2, w_sp, b_sp, w_vel, b_vel,
                                                  w_hid, b_hid, ws, out);
    } else {
        attn_main<false><<<1024, 256, 0, stream>>>(hs, obs1, obs2, w_sp, b_sp, w_vel, b_vel,
                                                   w_hid, b_hid, ws, out);
    }
}

// Round 4
// 128.950 us; speedup vs baseline: 1.2388x; 1.0887x over previous
//
#include <hip/hip_runtime.h>
#include <string.h>

typedef float v2f __attribute__((ext_vector_type(2)));
#define PKFMA(a,b,c) __builtin_elementwise_fma((a),(b),(c))
#define PKMAX(a,b)   __builtin_elementwise_max((a),(b))
static __device__ __forceinline__ v2f vsplat(float s) { return (v2f){s, s}; }
static __device__ __forceinline__ v2f shfl_xor_v2(v2f x, int m) {
    double d = __builtin_bit_cast(double, x);
    d = __shfl_xor(d, m, 64);
    return __builtin_bit_cast(v2f, d);
}

// ---------------- workspace float offsets ----------------
#define WS_WQC   0        // wq@w_iq          128x128 row-major
#define WS_WKC   16384    // wk@w_ik          128x128 row-major
#define WS_WVC   32768    // wv@w_iv          128x128 row-major
#define WS_MOW   49152    // mha_out_w@out_w  128x128 row-major
#define WS_GQ    65536    // [64][128]: cols 0..63 G, 64..95 Gs, 96..127 Gd
#define WS_G0Q   73728    // [128] biases in same col order
#define WS_FALL  73856    // [128][128]: rows 0..31 Fsp, 32..63 Fdv, 64..127 Fhid
#define WS_FB    90240    // [128]
#define WS_HID   90368    // [128 batches][64][64] relu(hs@w_hid+b_hid)
#define WS_NEED_HID_BYTES ((size_t)(90368 + 128*64*64) * 4)

// P1: weight products (+ per-batch hid into ws when workspace allows)
__global__ __launch_bounds__(256) void precompute1(
    const float* __restrict__ wq, const float* __restrict__ wk,
    const float* __restrict__ wv, const float* __restrict__ in_proj_w,
    const float* __restrict__ mha_out_w, const float* __restrict__ out_w,
    const float* __restrict__ hs, const float* __restrict__ w_hid,
    const float* __restrict__ b_hid, float* __restrict__ ws)
{
    __shared__ __align__(16) float sbuf[4224];
    const int tid = threadIdx.x;

    if (blockIdx.x < 256) {
        const int mat  = blockIdx.x >> 6;
        const int rp   = blockIdx.x & 63;
        const int rsel = tid >> 7;
        const int col  = tid & 127;
        const int r    = 2 * rp + rsel;
        const float* A; const float* Bm; int ldb; float* C;
        if (mat == 0)      { A = wq;        Bm = in_proj_w;       ldb = 384; C = ws + WS_WQC; }
        else if (mat == 1) { A = wk;        Bm = in_proj_w + 128; ldb = 384; C = ws + WS_WKC; }
        else if (mat == 2) { A = wv;        Bm = in_proj_w + 256; ldb = 384; C = ws + WS_WVC; }
        else               { A = mha_out_w; Bm = out_w;           ldb = 128; C = ws + WS_MOW; }
        sbuf[tid] = A[r * 128 + col];
        __syncthreads();
        float acc = 0.f;
        #pragma unroll 8
        for (int d = 0; d < 128; ++d) acc = fmaf(sbuf[rsel * 128 + d], Bm[d * ldb + col], acc);
        C[r * 128 + col] = acc;
    } else {
        const int b2 = blockIdx.x - 256;
        const int b = b2 >> 1, half = b2 & 1;
        const float4* src = (const float4*)(hs + b * 8192 + half * 4096);
        for (int k = tid; k < 1024; k += 256) {
            const int row = k >> 5, c = k & 31;
            *(float4*)&sbuf[row * 132 + 4 * c] = src[k];
        }
        __syncthreads();
        const int ty = tid >> 4, tx = tid & 15;
        float a0c[4] = {0,0,0,0}, a1c[4] = {0,0,0,0};
        for (int d0 = 0; d0 < 128; d0 += 4) {
            const float4 a0 = *(const float4*)&sbuf[(2*ty+0)*132 + d0];
            const float4 a1 = *(const float4*)&sbuf[(2*ty+1)*132 + d0];
            const float* a0p = (const float*)&a0;
            const float* a1p = (const float*)&a1;
            #pragma unroll
            for (int dd = 0; dd < 4; ++dd) {
                const float4 w4 = *(const float4*)&w_hid[(d0+dd)*64 + 4*tx];
                a0c[0] = fmaf(a0p[dd], w4.x, a0c[0]); a0c[1] = fmaf(a0p[dd], w4.y, a0c[1]);
                a0c[2] = fmaf(a0p[dd], w4.z, a0c[2]); a0c[3] = fmaf(a0p[dd], w4.w, a0c[3]);
                a1c[0] = fmaf(a1p[dd], w4.x, a1c[0]); a1c[1] = fmaf(a1p[dd], w4.y, a1c[1]);
                a1c[2] = fmaf(a1p[dd], w4.z, a1c[2]); a1c[3] = fmaf(a1p[dd], w4.w, a1c[3]);
            }
        }
        const float4 bh = *(const float4*)&b_hid[4*tx];
        float* dst = ws + WS_HID + b * 4096 + (32*half + 2*ty) * 64 + 4*tx;
        *(float4*)dst        = make_float4(fmaxf(a0c[0]+bh.x,0.f), fmaxf(a0c[1]+bh.y,0.f),
                                           fmaxf(a0c[2]+bh.z,0.f), fmaxf(a0c[3]+bh.w,0.f));
        *(float4*)(dst + 64) = make_float4(fmaxf(a1c[0]+bh.x,0.f), fmaxf(a1c[1]+bh.y,0.f),
                                           fmaxf(a1c[2]+bh.z,0.f), fmaxf(a1c[3]+bh.w,0.f));
    }
}

// P2: derived fused tensors GQ / g0q / F_all / fb
__global__ __launch_bounds__(128) void precompute2(
    const float* __restrict__ b_sp, const float* __restrict__ b_vel,
    const float* __restrict__ in_proj_b, const float* __restrict__ mha_out_b,
    const float* __restrict__ out_w, const float* __restrict__ out_b,
    float* __restrict__ ws)
{
    const float* Wqc = ws + WS_WQC;
    const float* Wkc = ws + WS_WKC;
    const float* Wvc = ws + WS_WVC;
    const float* Mow = ws + WS_MOW;
    const int bid = blockIdx.x, tid = threadIdx.x;
    __shared__ float sa[128];

    if (bid < 64) {
        const int k = bid;
        sa[tid] = Wqc[(32 + k) * 128 + tid];
        __syncthreads();
        const int j = tid;
        const int pj = (j < 64) ? 32 + j : ((j < 96) ? j - 64 : j);
        const float* brow = Wkc + pj * 128;
        float acc = 0.f;
        #pragma unroll 8
        for (int d = 0; d < 128; ++d) acc = fmaf(sa[d], brow[d], acc);
        ws[WS_GQ + k * 128 + j] = acc;
    } else if (bid < 192) {
        const int k2 = bid - 64;
        const int srcRow = (k2 < 32) ? k2 : ((k2 < 64) ? 96 + (k2 - 32) : 32 + (k2 - 64));
        sa[tid] = Wvc[srcRow * 128 + tid];
        __syncthreads();
        float acc = 0.f;
        #pragma unroll 8
        for (int m = 0; m < 128; ++m) acc = fmaf(sa[m], Mow[m * 128 + tid], acc);
        ws[WS_FALL + k2 * 128 + tid] = acc;
    } else if (bid == 192) {
        float acc = out_b[tid];
        #pragma unroll 8
        for (int m = 0; m < 128; ++m) {
            acc = fmaf(in_proj_b[256 + m], Mow[m * 128 + tid], acc);
            acc = fmaf(mha_out_b[m], out_w[m * 128 + tid], acc);
        }
        ws[WS_FB + tid] = acc;
    } else {
        float qc = in_proj_b[tid];  // b_iq
        #pragma unroll 4
        for (int s = 0; s < 32; ++s) {
            qc = fmaf(fmaxf(b_sp[s], 0.f),  Wqc[s * 128 + tid], qc);
            qc = fmaf(fmaxf(b_vel[s], 0.f), Wqc[(96 + s) * 128 + tid], qc);
        }
        sa[tid] = qc;
        __syncthreads();
        const int j = tid;
        const int pj = (j < 64) ? 32 + j : ((j < 96) ? j - 64 : j);
        const float* brow = Wkc + pj * 128;
        float acc = 0.f;
        #pragma unroll 8
        for (int d = 0; d < 128; ++d) acc = fmaf(sa[d], brow[d], acc);
        ws[WS_G0Q + j] = acc;
    }
}

// ---------------- attn_main v4: 4 rows/wave, packed fp32, one barrier ----------------
// LDS floats: s_hid 64x66 (4224) | s_obs 256 | per-wave 768:
//   tt[4][64] (t -> ssp|sdv), qq[4][64] (qs|qd -> ah), aa[64][4] (attn)
#define L_OBS  4224
#define L_WV   4480
// total 4480 + 4*768 = 7552 floats = 30.2 KB

template <bool HIDWS>
__global__ __launch_bounds__(256) void attn_main(
    const float* __restrict__ hs, const float* __restrict__ obs1,
    const float* __restrict__ obs2,
    const float* __restrict__ w_sp, const float* __restrict__ b_sp,
    const float* __restrict__ w_vel, const float* __restrict__ b_vel,
    const float* __restrict__ w_hid, const float* __restrict__ b_hid,
    const float* __restrict__ ws, float* __restrict__ out)
{
    const int tid = threadIdx.x;
    const int l   = tid & 63;
    const int w   = tid >> 6;
    const int b   = blockIdx.x >> 2;
    const int i0  = (blockIdx.x & 3) * 16;
    const int rg0 = i0 + 4 * w;          // 4 rows: rg0..rg0+3

    const float* GQ   = ws + WS_GQ;
    const float* g0q  = ws + WS_G0Q;
    const float* Fall = ws + WS_FALL;
    const float* fbv  = ws + WS_FB;

    __shared__ __align__(16) float smem[7552];
    float* const s_hid = smem;                 // stride 66
    float* const s_obs = smem + L_OBS;         // [j][4] = {o2x,o2y,vx,vy}
    float* const tt = smem + L_WV + w * 768;         // [r][64]
    float* const qq = smem + L_WV + w * 768 + 256;   // [r][qs32|qd32]
    float* const aa = smem + L_WV + w * 768 + 512;   // [j][4]

    // ---- staging ----
    if (tid < 64) {
        const int g = b * 64 + tid;
        const float2 o2 = ((const float2*)obs2)[g];
        const float2 o1 = ((const float2*)obs1)[g];
        *(float4*)&s_obs[tid * 4] = make_float4(o2.x, o2.y, o2.x - o1.x, o2.y - o1.y);
    }
    if (HIDWS) {
        const float4* src = (const float4*)(ws + WS_HID + b * 4096);
        #pragma unroll
        for (int k = tid; k < 1024; k += 256) {
            const int row = k >> 4, c4 = (k & 15) * 4;
            const float4 v = src[k];
            *(v2f*)&s_hid[row * 66 + c4]     = (v2f){v.x, v.y};
            *(v2f*)&s_hid[row * 66 + c4 + 2] = (v2f){v.z, v.w};
        }
    } else {
        const int r = tid >> 2, qseg = (tid & 3) * 16;
        float acc[16];
        #pragma unroll
        for (int c = 0; c < 16; ++c) acc[c] = b_hid[qseg + c];
        for (int k = 0; k < 128; ++k) {
            const float a = hs[b * 8192 + r * 128 + k];
            #pragma unroll
            for (int c4 = 0; c4 < 4; ++c4) {
                const float4 w4 = *(const float4*)&w_hid[k * 64 + qseg + 4 * c4];
                acc[4*c4+0] = fmaf(a, w4.x, acc[4*c4+0]);
                acc[4*c4+1] = fmaf(a, w4.y, acc[4*c4+1]);
                acc[4*c4+2] = fmaf(a, w4.z, acc[4*c4+2]);
                acc[4*c4+3] = fmaf(a, w4.w, acc[4*c4+3]);
            }
        }
        #pragma unroll
        for (int c = 0; c < 16; c += 2)
            *(v2f*)&s_hid[r * 66 + qseg + c] =
                (v2f){fmaxf(acc[c], 0.f), fmaxf(acc[c+1], 0.f)};
    }
    __syncthreads();
    // ---- no more block barriers: wave-private phases below ----

    // ---- phase 3: cols {2l,2l+1} of [t | qs | qd] = hid[row] @ GQ + g0q ----
    {
        const v2f bias = *(const v2f*)&g0q[2 * l];
        v2f acc0 = bias, acc1 = bias, acc2 = bias, acc3 = bias;
        for (int k0 = 0; k0 < 64; k0 += 2) {
            const v2f g0 = *(const v2f*)&GQ[k0 * 128 + 2 * l];
            const v2f g1 = *(const v2f*)&GQ[(k0 + 1) * 128 + 2 * l];
            const v2f h0 = *(const v2f*)&s_hid[(rg0 + 0) * 66 + k0];
            const v2f h1 = *(const v2f*)&s_hid[(rg0 + 1) * 66 + k0];
            const v2f h2 = *(const v2f*)&s_hid[(rg0 + 2) * 66 + k0];
            const v2f h3 = *(const v2f*)&s_hid[(rg0 + 3) * 66 + k0];
            acc0 = PKFMA(vsplat(h0.x), g0, PKFMA(vsplat(h0.y), g1, acc0));
            acc1 = PKFMA(vsplat(h1.x), g0, PKFMA(vsplat(h1.y), g1, acc1));
            acc2 = PKFMA(vsplat(h2.x), g0, PKFMA(vsplat(h2.y), g1, acc2));
            acc3 = PKFMA(vsplat(h3.x), g0, PKFMA(vsplat(h3.y), g1, acc3));
        }
        if (l < 32) {
            const int c = 2 * l;
            *(v2f*)&tt[0 * 64 + c] = acc0;  *(v2f*)&tt[1 * 64 + c] = acc1;
            *(v2f*)&tt[2 * 64 + c] = acc2;  *(v2f*)&tt[3 * 64 + c] = acc3;
        } else {
            const int c = 2 * l - 64;
            *(v2f*)&qq[0 * 64 + c] = acc0;  *(v2f*)&qq[1 * 64 + c] = acc1;
            *(v2f*)&qq[2 * 64 + c] = acc2;  *(v2f*)&qq[3 * 64 + c] = acc3;
        }
    }

    // ---- phase 4: sc[r] = t[r] . hid[l] ----
    float sc[4];
    {
        v2f s0 = (v2f){0.f,0.f}, s1 = s0, s2 = s0, s3 = s0;
        const float* hl = &s_hid[l * 66];
        for (int c0 = 0; c0 < 64; c0 += 2) {
            const v2f h2 = *(const v2f*)&hl[c0];
            s0 = PKFMA(*(const v2f*)&tt[0 * 64 + c0], h2, s0);
            s1 = PKFMA(*(const v2f*)&tt[1 * 64 + c0], h2, s1);
            s2 = PKFMA(*(const v2f*)&tt[2 * 64 + c0], h2, s2);
            s3 = PKFMA(*(const v2f*)&tt[3 * 64 + c0], h2, s3);
        }
        sc[0] = s0.x + s0.y; sc[1] = s1.x + s1.y;
        sc[2] = s2.x + s2.y; sc[3] = s3.x + s3.y;
    }

    // ---- phase 5: scores + packed softmax; attn -> aa[j][4] ----
    {
        const float4 oj = *(const float4*)&s_obs[4 * l];
        float rx[4], ry[4], dx[4], dy[4];
        #pragma unroll
        for (int r = 0; r < 4; ++r) {
            const float4 oi = *(const float4*)&s_obs[4 * (rg0 + r)];
            rx[r] = oj.x - oi.x;  ry[r] = oj.y - oi.y;
            dx[r] = (oj.z - oi.z) * 4.f;  dy[r] = (oj.w - oi.w) * 4.f;
        }
        v2f acc[4] = {{0,0},{0,0},{0,0},{0,0}};
        for (int s0 = 0; s0 < 32; s0 += 2) {
            const v2f w0p = *(const v2f*)&w_sp[s0];
            const v2f w1p = *(const v2f*)&w_sp[32 + s0];
            const v2f bsp = *(const v2f*)&b_sp[s0];
            const v2f u0p = *(const v2f*)&w_vel[s0];
            const v2f u1p = *(const v2f*)&w_vel[32 + s0];
            const v2f bvp = *(const v2f*)&b_vel[s0];
            #pragma unroll
            for (int r = 0; r < 4; ++r) {
                const v2f qs2 = *(const v2f*)&qq[r * 64 + s0];
                const v2f qd2 = *(const v2f*)&qq[r * 64 + 32 + s0];
                const v2f esp = PKMAX(PKFMA(vsplat(rx[r]), w0p,
                                     PKFMA(vsplat(ry[r]), w1p, bsp)), vsplat(0.f));
                acc[r] = PKFMA(qs2, esp, acc[r]);
                const v2f edv = PKMAX(PKFMA(vsplat(dx[r]), u0p,
                                     PKFMA(vsplat(dy[r]), u1p, bvp)), vsplat(0.f));
                acc[r] = PKFMA(qd2, edv, acc[r]);
            }
        }
        const float scale = 0.08838834764831845f;  // 1/sqrt(128)
        v2f p01 = (v2f){(sc[0] + acc[0].x + acc[0].y) * scale,
                        (sc[1] + acc[1].x + acc[1].y) * scale};
        v2f p23 = (v2f){(sc[2] + acc[2].x + acc[2].y) * scale,
                        (sc[3] + acc[3].x + acc[3].y) * scale};
        v2f m01 = p01, m23 = p23;
        #pragma unroll
        for (int off = 32; off > 0; off >>= 1) {
            m01 = PKMAX(m01, shfl_xor_v2(m01, off));
            m23 = PKMAX(m23, shfl_xor_v2(m23, off));
        }
        v2f e01 = (v2f){__expf(p01.x - m01.x), __expf(p01.y - m01.y)};
        v2f e23 = (v2f){__expf(p23.x - m23.x), __expf(p23.y - m23.y)};
        v2f u01 = e01, u23 = e23;
        #pragma unroll
        for (int off = 32; off > 0; off >>= 1) {
            u01 = u01 + shfl_xor_v2(u01, off);
            u23 = u23 + shfl_xor_v2(u23, off);
        }
        *(float4*)&aa[4 * l] = make_float4(e01.x / u01.x, e01.y / u01.y,
                                           e23.x / u23.x, e23.y / u23.y);
    }

    // ---- phase 6a: pooled embeds -> tt[r] = [ssp 0..31 | sdv 32..63] ----
    {
        const int r = l >> 4, s = l & 15;   // lane covers slots {s, s+16}
        const v2f w0p = (v2f){w_sp[s],        w_sp[s + 16]};
        const v2f w1p = (v2f){w_sp[32 + s],   w_sp[48 + s]};
        const v2f bsp = (v2f){b_sp[s],        b_sp[s + 16]};
        const v2f u0p = (v2f){w_vel[s],       w_vel[s + 16]};
        const v2f u1p = (v2f){w_vel[32 + s],  w_vel[48 + s]};
        const v2f bvp = (v2f){b_vel[s],       b_vel[s + 16]};
        const float4 oi = *(const float4*)&s_obs[4 * (rg0 + r)];
        v2f asp = (v2f){0.f, 0.f}, adv = asp;
        for (int j = 0; j < 64; ++j) {
            const float a = aa[4 * j + r];
            const float4 o4 = *(const float4*)&s_obs[4 * j];
            const float rxx = o4.x - oi.x, ryy = o4.y - oi.y;
            const float dxx = (o4.z - oi.z) * 4.f, dyy = (o4.w - oi.w) * 4.f;
            const v2f esp = PKMAX(PKFMA(vsplat(rxx), w0p,
                                 PKFMA(vsplat(ryy), w1p, bsp)), vsplat(0.f));
            asp = PKFMA(vsplat(a), esp, asp);
            const v2f edv = PKMAX(PKFMA(vsplat(dxx), u0p,
                                 PKFMA(vsplat(dyy), u1p, bvp)), vsplat(0.f));
            adv = PKFMA(vsplat(a), edv, adv);
        }
        tt[r * 64 + s]           = asp.x;
        tt[r * 64 + s + 16]      = asp.y;
        tt[r * 64 + 32 + s]      = adv.x;
        tt[r * 64 + 48 + s]      = adv.y;
    }

    // ---- phase 6b: ah[r][l] = attn[r] @ hid -> qq[r][l] ----
    {
        float ah0 = 0.f, ah1 = 0.f, ah2 = 0.f, ah3 = 0.f;
        for (int j = 0; j < 64; j += 2) {
            const float4 a0 = *(const float4*)&aa[4 * j];
            const float4 a1 = *(const float4*)&aa[4 * j + 4];
            const float h0 = s_hid[j * 66 + l];
            const float h1 = s_hid[(j + 1) * 66 + l];
            ah0 = fmaf(a0.x, h0, fmaf(a1.x, h1, ah0));
            ah1 = fmaf(a0.y, h0, fmaf(a1.y, h1, ah1));
            ah2 = fmaf(a0.z, h0, fmaf(a1.z, h1, ah2));
            ah3 = fmaf(a0.w, h0, fmaf(a1.w, h1, ah3));
        }
        qq[0 * 64 + l] = ah0;  qq[1 * 64 + l] = ah1;
        qq[2 * 64 + l] = ah2;  qq[3 * 64 + l] = ah3;
    }

    // ---- phase 7: out = [ssp|sdv] @ Fall[0:64] + ah @ Fall[64:128] + fb ----
    {
        const v2f fb2 = *(const v2f*)&fbv[2 * l];
        v2f o0 = fb2, o1 = fb2, o2 = fb2, o3 = fb2;
        for (int k = 0; k < 64; k += 2) {
            const v2f f0 = *(const v2f*)&Fall[k * 128 + 2 * l];
            const v2f f1 = *(const v2f*)&Fall[(k + 1) * 128 + 2 * l];
            const v2f A0 = *(const v2f*)&tt[0 * 64 + k];
            const v2f A1 = *(const v2f*)&tt[1 * 64 + k];
            const v2f A2 = *(const v2f*)&tt[2 * 64 + k];
            const v2f A3 = *(const v2f*)&tt[3 * 64 + k];
            o0 = PKFMA(vsplat(A0.x), f0, PKFMA(vsplat(A0.y), f1, o0));
            o1 = PKFMA(vsplat(A1.x), f0, PKFMA(vsplat(A1.y), f1, o1));
            o2 = PKFMA(vsplat(A2.x), f0, PKFMA(vsplat(A2.y), f1, o2));
            o3 = PKFMA(vsplat(A3.x), f0, PKFMA(vsplat(A3.y), f1, o3));
        }
        for (int k = 0; k < 64; k += 2) {
            const v2f f0 = *(const v2f*)&Fall[(64 + k) * 128 + 2 * l];
            const v2f f1 = *(const v2f*)&Fall[(65 + k) * 128 + 2 * l];
            const v2f A0 = *(const v2f*)&qq[0 * 64 + k];
            const v2f A1 = *(const v2f*)&qq[1 * 64 + k];
            const v2f A2 = *(const v2f*)&qq[2 * 64 + k];
            const v2f A3 = *(const v2f*)&qq[3 * 64 + k];
            o0 = PKFMA(vsplat(A0.x), f0, PKFMA(vsplat(A0.y), f1, o0));
            o1 = PKFMA(vsplat(A1.x), f0, PKFMA(vsplat(A1.y), f1, o1));
            o2 = PKFMA(vsplat(A2.x), f0, PKFMA(vsplat(A2.y), f1, o2));
            o3 = PKFMA(vsplat(A3.x), f0, PKFMA(vsplat(A3.y), f1, o3));
        }
        const int gr = (b * 64 + rg0) * 128 + 2 * l;
        *(v2f*)&out[gr]           = o0;
        *(v2f*)&out[gr + 128]     = o1;
        *(v2f*)&out[gr + 256]     = o2;
        *(v2f*)&out[gr + 384]     = o3;
    }
}

extern "C" void kernel_launch(void* const* d_in, const int* in_sizes, int n_in,
                              void* d_out, int out_size, void* d_ws, size_t ws_size,
                              hipStream_t stream) {
    const float* hs        = (const float*)d_in[0];
    const float* obs1      = (const float*)d_in[1];
    const float* obs2      = (const float*)d_in[2];
    const float* w_sp      = (const float*)d_in[3];
    const float* b_sp      = (const float*)d_in[4];
    const float* w_vel     = (const float*)d_in[5];
    const float* b_vel     = (const float*)d_in[6];
    const float* w_hid     = (const float*)d_in[7];
    const float* b_hid     = (const float*)d_in[8];
    const float* wq        = (const float*)d_in[9];
    const float* wk        = (const float*)d_in[10];
    const float* wv        = (const float*)d_in[11];
    const float* in_proj_w = (const float*)d_in[12];
    const float* in_proj_b = (const float*)d_in[13];
    const float* mha_out_w = (const float*)d_in[14];
    const float* mha_out_b = (const float*)d_in[15];
    const float* out_w     = (const float*)d_in[16];
    const float* out_b     = (const float*)d_in[17];
    float* ws  = (float*)d_ws;
    float* out = (float*)d_out;

    const bool hidws = (ws_size >= WS_NEED_HID_BYTES);

    precompute1<<<hidws ? 512 : 256, 256, 0, stream>>>(
        wq, wk, wv, in_proj_w, mha_out_w, out_w, hs, w_hid, b_hid, ws);
    precompute2<<<194, 128, 0, stream>>>(
        b_sp, b_vel, in_proj_b, mha_out_b, out_w, out_b, ws);
    if (hidws) {
        attn_main<true><<<512, 256, 0, stream>>>(hs, obs1, obs2, w_sp, b_sp, w_vel, b_vel,
                                                 w_hid, b_hid, ws, out);
    } else {
        attn_main<false><<<512, 256, 0, stream>>>(hs, obs1, obs2, w_sp, b_sp, w_vel, b_vel,
                                                  w_hid, b_hid, ws, out);
    }
}